// Round 3
// baseline (989.477 us; speedup 1.0000x reference)
//
#include <hip/hip_runtime.h>

// FNO spectral block: x(32,256,4096), weight(256,256,128,2) -> out (dtype of x).
// Runtime dtype probe (fp32 vs bf16 dataset); bf16-MFMA internally, fp32 acc.
// probe -> basis -> gemm1 (trunc rDFT, splitK=2) -> pack (sum+transpose) ->
// mix (per-o coalesced weight stream) -> gemm2 (irDFT + LeakyReLU + residual).

typedef unsigned short u16;
typedef unsigned int   u32;
typedef __attribute__((ext_vector_type(8))) short bf16x8;
typedef __attribute__((ext_vector_type(4))) float f32x4;

#define NROWS 8192
#define MLEN  4096

__device__ __forceinline__ u16 f2b(float f) {           // fp32 -> bf16 RNE
  u32 u = __float_as_uint(f);
  u += 0x7fffu + ((u >> 16) & 1u);
  return (u16)(u >> 16);
}
__device__ __forceinline__ float blo(u32 p) { return __uint_as_float(p << 16); }
__device__ __forceinline__ float bhi(u32 p) { return __uint_as_float(p & 0xffff0000u); }

// ------------------------------------------------------------- dtype probe
__global__ void probe_kernel(const u16* __restrict__ x16, int* __restrict__ flag) {
  __shared__ int cnt;
  if (threadIdx.x == 0) cnt = 0;
  __syncthreads();
  int c = 0;
  for (int j = threadIdx.x; j < 4096; j += 256) {
    u32 e = (x16[j] >> 7) & 0xFFu;
    if (e >= 0x8Fu) ++c;
  }
  atomicAdd(&cnt, c);
  __syncthreads();
  if (threadIdx.x == 0) flag[0] = (cnt > 256) ? 0 : 1;   // 0=fp32, 1=bf16
}

// ---------------------------------------------------------------- basis
__global__ void basis_kernel(u16* __restrict__ Bas1, u16* __restrict__ Bas2) {
  int t = blockIdx.x;           // 0..4095
  int c = threadIdx.x;          // 0..255
  int m = c & 127;
  int idx = (m * t) & 4095;
  float theta = (float)idx * (6.283185307179586f / 4096.0f);
  float s, cth;
  __sincosf(theta, &s, &cth);
  float v = (c < 128) ? cth : -s;
  u16 bv = f2b(v);
  Bas2[t * 256 + c] = bv;
  Bas1[c * 4096 + t] = bv;
}

// ---------------------------------------------------------------- GEMM (NT)
// C = A(MxK,row,lda) * Bt(NxK,row,ldb)^T. K per split-part; part = blockIdx.z.
// EPI=0: C0[(z*256+col)*ldc + row] = fp32   (forward DFT partial, transposed)
// EPI=1: out[row*ldc+col] = x + leakyrelu(C), dtype per mode.
template <int BM, int BN, int EPI, bool ADUAL>
__global__ __launch_bounds__(256)
void gemm_nt(const void* __restrict__ A, const u16* __restrict__ Bt,
             int K, int lda, int ldb,
             float* __restrict__ C0, int ldc,
             const void* __restrict__ xres, void* __restrict__ outp,
             const int* __restrict__ flag) {
  constexpr int LD = 72;                 // 64+8 pad: <=2-way LDS conflicts (free)
  constexpr int FM = BM / 32;
  constexpr int FN = BN / 32;
  __shared__ u16 As[BM * LD];
  __shared__ u16 Bs[BN * LD];
  const int mode = (ADUAL || EPI == 1) ? flag[0] : 1;
  const int tid = threadIdx.x;
  const int bn0 = blockIdx.x * BN;
  const int bm0 = blockIdx.y * BM;
  const int k0 = blockIdx.z * K;
  const int lane = tid & 63;
  const int wave = tid >> 6;
  const int wm = wave >> 1, wn = wave & 1;
  const int l15 = lane & 15, q4 = lane >> 4;

  f32x4 acc[FM][FN] = {};

  for (int kt = 0; kt < K; kt += 64) {
    __syncthreads();
    if (!ADUAL || mode == 1) {
      const u16* Ab = (const u16*)A;
#pragma unroll
      for (int q = tid; q < BM * 8; q += 256) {
        int row = q >> 3, c8 = q & 7;
        *(uint4*)&As[row * LD + c8 * 8] =
            *(const uint4*)&Ab[(size_t)(bm0 + row) * lda + k0 + kt + c8 * 8];
      }
    } else {
      const float* Af = (const float*)A;
#pragma unroll
      for (int q = tid; q < BM * 8; q += 256) {
        int row = q >> 3, c8 = q & 7;
        const float* src = &Af[(size_t)(bm0 + row) * lda + k0 + kt + c8 * 8];
        float4 f0 = *(const float4*)src;
        float4 f1 = *(const float4*)(src + 4);
        u16 tmp[8] = {f2b(f0.x), f2b(f0.y), f2b(f0.z), f2b(f0.w),
                      f2b(f1.x), f2b(f1.y), f2b(f1.z), f2b(f1.w)};
        *(uint4*)&As[row * LD + c8 * 8] = *(const uint4*)tmp;
      }
    }
#pragma unroll
    for (int q = tid; q < BN * 8; q += 256) {
      int row = q >> 3, c8 = q & 7;
      *(uint4*)&Bs[row * LD + c8 * 8] =
          *(const uint4*)&Bt[(size_t)(bn0 + row) * ldb + k0 + kt + c8 * 8];
    }
    __syncthreads();
#pragma unroll
    for (int kk = 0; kk < 2; ++kk) {
      const int ko = kk * 32 + q4 * 8;
      bf16x8 af[FM], bfr[FN];
#pragma unroll
      for (int mi = 0; mi < FM; ++mi)
        af[mi] = *(const bf16x8*)&As[(wm * (BM / 2) + mi * 16 + l15) * LD + ko];
#pragma unroll
      for (int ni = 0; ni < FN; ++ni)
        bfr[ni] = *(const bf16x8*)&Bs[(wn * (BN / 2) + ni * 16 + l15) * LD + ko];
#pragma unroll
      for (int mi = 0; mi < FM; ++mi)
#pragma unroll
        for (int ni = 0; ni < FN; ++ni)
          acc[mi][ni] = __builtin_amdgcn_mfma_f32_16x16x32_bf16(
              af[mi], bfr[ni], acc[mi][ni], 0, 0, 0);
    }
  }

#pragma unroll
  for (int mi = 0; mi < FM; ++mi) {
#pragma unroll
    for (int ni = 0; ni < FN; ++ni) {
      const int col = bn0 + wn * (BN / 2) + ni * 16 + l15;
#pragma unroll
      for (int r = 0; r < 4; ++r) {
        const int row = bm0 + wm * (BM / 2) + mi * 16 + q4 * 4 + r;
        float v = acc[mi][ni][r];
        if (EPI == 0) {
          C0[(size_t)(blockIdx.z * 256 + col) * ldc + row] = v;
        } else {
          size_t idx = (size_t)row * ldc + col;
          float lr = (v >= 0.f ? v : 0.2f * v);
          if (mode == 1) {
            float xv = blo((u32)((const u16*)xres)[idx]);
            ((u16*)outp)[idx] = f2b(xv + lr);
          } else {
            float xv = ((const float*)xres)[idx];
            ((float*)outp)[idx] = xv + lr;
          }
        }
      }
    }
  }
}

// ---------------------------------------------------------------- pack
// Sum 2 split-K parts of Xt and transpose into Xp[ic][m][b] packed u32(re,im bf16).
// Xt layout: [z*256 + c][row], c<128 Re, c>=128 Im, row = b*256+ic.
// Block: m-tile 8 x ic-tile 32, all 32 b. Grid (16, 8).
__global__ __launch_bounds__(256)
void pack_kernel(const float* __restrict__ Xt, u32* __restrict__ Xp) {
  __shared__ u32 Ls[8 * 32 * 33];        // [m'][ic][b], b padded to 33
  const int tid = threadIdx.x;
  const int m0 = blockIdx.x * 8;
  const int ic0 = blockIdx.y * 32;
  const int icr = tid & 31, bq = tid >> 5;         // read mapping
#pragma unroll
  for (int mp = 0; mp < 8; ++mp) {
    const int c = m0 + mp;
#pragma unroll
    for (int pass = 0; pass < 4; ++pass) {
      int b = pass * 8 + bq;
      size_t row = (size_t)b * 256 + ic0 + icr;
      float re = Xt[(size_t)c * NROWS + row] + Xt[(size_t)(256 + c) * NROWS + row];
      float im = Xt[(size_t)(128 + c) * NROWS + row] + Xt[(size_t)(384 + c) * NROWS + row];
      Ls[(mp * 32 + icr) * 33 + b] = (u32)f2b(re) | ((u32)f2b(im) << 16);
    }
  }
  __syncthreads();
  const int bw = tid & 31, icq = tid >> 5;         // write mapping
#pragma unroll
  for (int mp = 0; mp < 8; ++mp) {
#pragma unroll
    for (int pass = 0; pass < 4; ++pass) {
      int icw = pass * 8 + icq;
      Xp[((size_t)(ic0 + icw) * 128 + m0 + mp) * 32 + bw] =
          Ls[(mp * 32 + icw) * 33 + bw];
    }
  }
}

// ---------------------------------------------------------------- mode mix
// One block per output channel o: weight row w[o] (256 KB fp32 / 128 KB bf16)
// streamed fully coalesced; X from Xp[ic][m][b] (4 MB, L2-resident).
// Block 1024 thr: mp = tid&63 -> modes (2mp, 2mp+1); bg = tid>>6 -> b pair.
// Writes Yp bf16 pre-scaled for inverse GEMM.
__global__ __launch_bounds__(1024)
void mix_kernel(const u32* __restrict__ Xp, const void* __restrict__ w,
                u16* __restrict__ Yp, const int* __restrict__ flag) {
  const int o = blockIdx.x;
  const int tid = threadIdx.x;
  const int mp = tid & 63, m = mp * 2;
  const int b0 = (tid >> 6) * 2;
  const int mode = flag[0];

  float ar[2][2] = {}, ai[2][2] = {};    // [b][mi]

  if (mode == 0) {
    const float* wb = (const float*)w + 2u * ((size_t)o * 32768 + m);
#pragma unroll 4
    for (int ic = 0; ic < 256; ++ic) {
      uint2 xa = *(const uint2*)&Xp[((size_t)ic * 128 + m) * 32 + b0];
      uint2 xb = *(const uint2*)&Xp[((size_t)ic * 128 + m + 1) * 32 + b0];
      float4 wp = *(const float4*)&wb[(size_t)ic * 256];
      float wr0 = wp.x, wi0 = wp.y, wr1 = wp.z, wi1 = wp.w;
      float xr, xi;
      xr = blo(xa.x); xi = bhi(xa.x);
      ar[0][0] = fmaf(xr, wr0, fmaf(-xi, wi0, ar[0][0]));
      ai[0][0] = fmaf(xr, wi0, fmaf(xi, wr0, ai[0][0]));
      xr = blo(xa.y); xi = bhi(xa.y);
      ar[1][0] = fmaf(xr, wr0, fmaf(-xi, wi0, ar[1][0]));
      ai[1][0] = fmaf(xr, wi0, fmaf(xi, wr0, ai[1][0]));
      xr = blo(xb.x); xi = bhi(xb.x);
      ar[0][1] = fmaf(xr, wr1, fmaf(-xi, wi1, ar[0][1]));
      ai[0][1] = fmaf(xr, wi1, fmaf(xi, wr1, ai[0][1]));
      xr = blo(xb.y); xi = bhi(xb.y);
      ar[1][1] = fmaf(xr, wr1, fmaf(-xi, wi1, ar[1][1]));
      ai[1][1] = fmaf(xr, wi1, fmaf(xi, wr1, ai[1][1]));
    }
  } else {
    const u32* wb = (const u32*)w + (size_t)o * 32768 + m;
#pragma unroll 4
    for (int ic = 0; ic < 256; ++ic) {
      uint2 xa = *(const uint2*)&Xp[((size_t)ic * 128 + m) * 32 + b0];
      uint2 xb = *(const uint2*)&Xp[((size_t)ic * 128 + m + 1) * 32 + b0];
      uint2 wp = *(const uint2*)&wb[(size_t)ic * 128];
      float wr0 = blo(wp.x), wi0 = bhi(wp.x), wr1 = blo(wp.y), wi1 = bhi(wp.y);
      float xr, xi;
      xr = blo(xa.x); xi = bhi(xa.x);
      ar[0][0] = fmaf(xr, wr0, fmaf(-xi, wi0, ar[0][0]));
      ai[0][0] = fmaf(xr, wi0, fmaf(xi, wr0, ai[0][0]));
      xr = blo(xa.y); xi = bhi(xa.y);
      ar[1][0] = fmaf(xr, wr0, fmaf(-xi, wi0, ar[1][0]));
      ai[1][0] = fmaf(xr, wi0, fmaf(xi, wr0, ai[1][0]));
      xr = blo(xb.x); xi = bhi(xb.x);
      ar[0][1] = fmaf(xr, wr1, fmaf(-xi, wi1, ar[0][1]));
      ai[0][1] = fmaf(xr, wi1, fmaf(xi, wr1, ai[0][1]));
      xr = blo(xb.y); xi = bhi(xb.y);
      ar[1][1] = fmaf(xr, wr1, fmaf(-xi, wi1, ar[1][1]));
      ai[1][1] = fmaf(xr, wi1, fmaf(xi, wr1, ai[1][1]));
    }
  }

  const float sIm = 2.0f / 4096.0f;
#pragma unroll
  for (int jb = 0; jb < 2; ++jb) {
#pragma unroll
    for (int mi = 0; mi < 2; ++mi) {
      int b = b0 + jb, mm = m + mi;
      float sRe = (mm == 0) ? (1.0f / 4096.0f) : (2.0f / 4096.0f);
      size_t row2 = (size_t)(b * 256 + o) * 256;
      Yp[row2 + mm] = f2b(ar[jb][mi] * sRe);
      Yp[row2 + mm + 128] = f2b(ai[jb][mi] * sIm);
    }
  }
}

// ---------------------------------------------------------------- launch
extern "C" void kernel_launch(void* const* d_in, const int* in_sizes, int n_in,
                              void* d_out, int out_size, void* d_ws, size_t ws_size,
                              hipStream_t stream) {
  const void* x = d_in[0];                // (32,256,4096) fp32 or bf16
  const void* w = d_in[1];                // (256,256,128,2) fp32 or bf16

  char* ws = (char*)d_ws;
  int*   flag = (int*)(ws);                        // @0
  u16*   Bas1 = (u16*)(ws + (1u  << 20));          // 2 MB
  u16*   Bas2 = (u16*)(ws + (3u  << 20));          // 2 MB
  float* Xt   = (float*)(ws + (5u << 20));         // 2 x 8 MB split-K parts
  u32*   Xp   = (u32*)(ws + (21u << 20));          // 4 MB packed spectra
  u16*   Yp   = (u16*)(ws + (25u << 20));          // 4 MB

  probe_kernel<<<dim3(1), dim3(256), 0, stream>>>((const u16*)x, flag);
  basis_kernel<<<dim3(4096), dim3(256), 0, stream>>>(Bas1, Bas2);

  // forward truncated rDFT, split-K=2: x(8192x4096) * Bas1(256x4096)^T
  gemm_nt<64, 256, 0, true><<<dim3(1, 128, 2), dim3(256), 0, stream>>>(
      x, Bas1, MLEN / 2, MLEN, MLEN, Xt, NROWS, nullptr, nullptr, flag);

  // sum split-K parts + transpose to Xp[ic][m][b]
  pack_kernel<<<dim3(16, 8), dim3(256), 0, stream>>>(Xt, Xp);

  // per-mode complex channel mix -> Yp (bf16, irfft scaling folded in)
  mix_kernel<<<dim3(256), dim3(1024), 0, stream>>>(Xp, w, Yp, flag);

  // inverse DFT + LeakyReLU + residual
  gemm_nt<128, 128, 1, false><<<dim3(32, 64, 1), dim3(256), 0, stream>>>(
      Yp, Bas2, 256, 256, 256, nullptr, MLEN, x, d_out, flag);
}

// Round 4
// 577.590 us; speedup vs baseline: 1.7131x; 1.7131x over previous
//
#include <hip/hip_runtime.h>

// FNO spectral block: x(32,256,4096), weight(256,256,128,2) -> out (dtype of x).
// Runtime dtype probe (fp32 vs bf16); bf16-MFMA internally, fp32 accumulation.
// probe -> basis -> gemm1 (trunc rDFT, splitK=nz) -> pack (sum+transpose to
// Xp[ic][b][m]) -> mix (o-pair blocks, coalesced weight stream) ->
// gemm2 (irDFT + LeakyReLU + residual).

typedef unsigned short u16;
typedef unsigned int   u32;
typedef __attribute__((ext_vector_type(8))) short bf16x8;
typedef __attribute__((ext_vector_type(4))) float f32x4;

#define NROWS 8192
#define MLEN  4096

__device__ __forceinline__ u16 f2b(float f) {           // fp32 -> bf16 RNE
  u32 u = __float_as_uint(f);
  u += 0x7fffu + ((u >> 16) & 1u);
  return (u16)(u >> 16);
}
__device__ __forceinline__ float blo(u32 p) { return __uint_as_float(p << 16); }
__device__ __forceinline__ float bhi(u32 p) { return __uint_as_float(p & 0xffff0000u); }

// ------------------------------------------------------------- dtype probe
__global__ void probe_kernel(const u16* __restrict__ x16, int* __restrict__ flag) {
  __shared__ int cnt;
  if (threadIdx.x == 0) cnt = 0;
  __syncthreads();
  int c = 0;
  for (int j = threadIdx.x; j < 4096; j += 256) {
    u32 e = (x16[j] >> 7) & 0xFFu;
    if (e >= 0x8Fu) ++c;
  }
  atomicAdd(&cnt, c);
  __syncthreads();
  if (threadIdx.x == 0) flag[0] = (cnt > 256) ? 0 : 1;   // 0=fp32, 1=bf16
}

// ---------------------------------------------------------------- basis
__global__ void basis_kernel(u16* __restrict__ Bas1, u16* __restrict__ Bas2) {
  int t = blockIdx.x;           // 0..4095
  int c = threadIdx.x;          // 0..255
  int m = c & 127;
  int idx = (m * t) & 4095;
  float theta = (float)idx * (6.283185307179586f / 4096.0f);
  float s, cth;
  __sincosf(theta, &s, &cth);
  float v = (c < 128) ? cth : -s;
  u16 bv = f2b(v);
  Bas2[t * 256 + c] = bv;
  Bas1[c * 4096 + t] = bv;
}

// ---------------------------------------------------------------- GEMM (NT)
// C = A(MxK,row,lda) * Bt(NxK,row,ldb)^T. K per split-part; part = blockIdx.z.
// EPI=0: C0[(z*256+col)*ldc + row] = fp32   (forward DFT partial, transposed)
// EPI=1: out[row*ldc+col] = x + leakyrelu(C), dtype per mode.
template <int BM, int BN, int EPI, bool ADUAL>
__global__ __launch_bounds__(256)
void gemm_nt(const void* __restrict__ A, const u16* __restrict__ Bt,
             int K, int lda, int ldb,
             float* __restrict__ C0, int ldc,
             const void* __restrict__ xres, void* __restrict__ outp,
             const int* __restrict__ flag) {
  constexpr int LD = 72;                 // 64+8 pad: <=2-way LDS conflicts (free)
  constexpr int FM = BM / 32;
  constexpr int FN = BN / 32;
  __shared__ u16 As[BM * LD];
  __shared__ u16 Bs[BN * LD];
  const int mode = (ADUAL || EPI == 1) ? flag[0] : 1;
  const int tid = threadIdx.x;
  const int bn0 = blockIdx.x * BN;
  const int bm0 = blockIdx.y * BM;
  const int k0 = blockIdx.z * K;
  const int lane = tid & 63;
  const int wave = tid >> 6;
  const int wm = wave >> 1, wn = wave & 1;
  const int l15 = lane & 15, q4 = lane >> 4;

  f32x4 acc[FM][FN] = {};

  for (int kt = 0; kt < K; kt += 64) {
    __syncthreads();
    if (!ADUAL || mode == 1) {
      const u16* Ab = (const u16*)A;
#pragma unroll
      for (int q = tid; q < BM * 8; q += 256) {
        int row = q >> 3, c8 = q & 7;
        *(uint4*)&As[row * LD + c8 * 8] =
            *(const uint4*)&Ab[(size_t)(bm0 + row) * lda + k0 + kt + c8 * 8];
      }
    } else {
      const float* Af = (const float*)A;
#pragma unroll
      for (int q = tid; q < BM * 8; q += 256) {
        int row = q >> 3, c8 = q & 7;
        const float* src = &Af[(size_t)(bm0 + row) * lda + k0 + kt + c8 * 8];
        float4 f0 = *(const float4*)src;
        float4 f1 = *(const float4*)(src + 4);
        u16 tmp[8] = {f2b(f0.x), f2b(f0.y), f2b(f0.z), f2b(f0.w),
                      f2b(f1.x), f2b(f1.y), f2b(f1.z), f2b(f1.w)};
        *(uint4*)&As[row * LD + c8 * 8] = *(const uint4*)tmp;
      }
    }
#pragma unroll
    for (int q = tid; q < BN * 8; q += 256) {
      int row = q >> 3, c8 = q & 7;
      *(uint4*)&Bs[row * LD + c8 * 8] =
          *(const uint4*)&Bt[(size_t)(bn0 + row) * ldb + k0 + kt + c8 * 8];
    }
    __syncthreads();
#pragma unroll
    for (int kk = 0; kk < 2; ++kk) {
      const int ko = kk * 32 + q4 * 8;
      bf16x8 af[FM], bfr[FN];
#pragma unroll
      for (int mi = 0; mi < FM; ++mi)
        af[mi] = *(const bf16x8*)&As[(wm * (BM / 2) + mi * 16 + l15) * LD + ko];
#pragma unroll
      for (int ni = 0; ni < FN; ++ni)
        bfr[ni] = *(const bf16x8*)&Bs[(wn * (BN / 2) + ni * 16 + l15) * LD + ko];
#pragma unroll
      for (int mi = 0; mi < FM; ++mi)
#pragma unroll
        for (int ni = 0; ni < FN; ++ni)
          acc[mi][ni] = __builtin_amdgcn_mfma_f32_16x16x32_bf16(
              af[mi], bfr[ni], acc[mi][ni], 0, 0, 0);
    }
  }

#pragma unroll
  for (int mi = 0; mi < FM; ++mi) {
#pragma unroll
    for (int ni = 0; ni < FN; ++ni) {
      const int col = bn0 + wn * (BN / 2) + ni * 16 + l15;
#pragma unroll
      for (int r = 0; r < 4; ++r) {
        const int row = bm0 + wm * (BM / 2) + mi * 16 + q4 * 4 + r;
        float v = acc[mi][ni][r];
        if (EPI == 0) {
          C0[(size_t)(blockIdx.z * 256 + col) * ldc + row] = v;
        } else {
          size_t idx = (size_t)row * ldc + col;
          float lr = (v >= 0.f ? v : 0.2f * v);
          if (mode == 1) {
            float xv = blo((u32)((const u16*)xres)[idx]);
            ((u16*)outp)[idx] = f2b(xv + lr);
          } else {
            float xv = ((const float*)xres)[idx];
            ((float*)outp)[idx] = xv + lr;
          }
        }
      }
    }
  }
}

// ---------------------------------------------------------------- pack
// Sum nz split-K parts of Xt; transpose into Xp[ic][b][m] packed u32(re,im bf16).
// Xt: [z*256 + c][row], c<128 Re / c>=128 Im, row = b*256 + ic.
// Grid (32 b, 8 ic-tiles of 32), block 256.
__global__ __launch_bounds__(256)
void pack_kernel(const float* __restrict__ Xt, u32* __restrict__ Xp, int nz) {
  __shared__ u16 Lre[32 * 130];          // [ic][m], row stride 130: conflict-free
  __shared__ u16 Lim[32 * 130];
  const int tid = threadIdx.x;
  const int b = blockIdx.x;
  const int ic0 = blockIdx.y * 32;
  const int icr = tid & 31, cg = tid >> 5;         // read: lanes along ic
  const size_t rbase = (size_t)b * 256 + ic0 + icr;
  for (int cc = 0; cc < 32; ++cc) {
    const int c = cc * 8 + cg;                     // 0..255
    float s = 0.f;
    for (int z = 0; z < nz; ++z)
      s += Xt[(size_t)(z * 256 + c) * NROWS + rbase];
    u16 v = f2b(s);
    if (c < 128) Lre[icr * 130 + c] = v;
    else         Lim[icr * 130 + (c - 128)] = v;
  }
  __syncthreads();
  const int mw = tid & 127, ich = tid >> 7;        // write: lanes along m
#pragma unroll
  for (int i2 = 0; i2 < 16; ++i2) {
    int ic = i2 * 2 + ich;
    u32 v = (u32)Lre[ic * 130 + mw] | ((u32)Lim[ic * 130 + mw] << 16);
    Xp[((size_t)(ic0 + ic) * 32 + b) * 128 + mw] = v;
  }
}

// ---------------------------------------------------------------- mode mix
// Y[b,o,m] = sum_i X[b,i,m]*w[o,i,m] (complex). Block = (o-pair, b-half),
// 1024 thr: wave>>3 -> o_local, wave&7 -> b-pair, lane -> m-pair.
// Weight streamed fully contiguous; X from Xp[ic][b][m] coalesced.
// Writes Yp bf16 pre-scaled for inverse GEMM.
__global__ __launch_bounds__(1024)
void mix_kernel(const u32* __restrict__ Xp, const void* __restrict__ w,
                u16* __restrict__ Yp, const int* __restrict__ flag) {
  const int tid = threadIdx.x;
  const int wave = tid >> 6, lane = tid & 63;
  const int o = blockIdx.x * 2 + (wave >> 3);
  const int b0 = blockIdx.y * 16 + (wave & 7) * 2;
  const int m = lane * 2;
  const int mode = flag[0];

  float ar[2][2] = {}, ai[2][2] = {};    // [b][mi]

  if (mode == 0) {
    const float* wb = (const float*)w + 2u * ((size_t)o * 32768 + m);
#pragma unroll 4
    for (int ic = 0; ic < 256; ++ic) {
      float4 wp = *(const float4*)&wb[(size_t)ic * 256];
      uint2 xa = *(const uint2*)&Xp[((size_t)ic * 32 + b0) * 128 + m];
      uint2 xb = *(const uint2*)&Xp[((size_t)ic * 32 + b0 + 1) * 128 + m];
      float wr0 = wp.x, wi0 = wp.y, wr1 = wp.z, wi1 = wp.w;
      float xr, xi;
      xr = blo(xa.x); xi = bhi(xa.x);
      ar[0][0] = fmaf(xr, wr0, fmaf(-xi, wi0, ar[0][0]));
      ai[0][0] = fmaf(xr, wi0, fmaf(xi, wr0, ai[0][0]));
      xr = blo(xa.y); xi = bhi(xa.y);
      ar[0][1] = fmaf(xr, wr1, fmaf(-xi, wi1, ar[0][1]));
      ai[0][1] = fmaf(xr, wi1, fmaf(xi, wr1, ai[0][1]));
      xr = blo(xb.x); xi = bhi(xb.x);
      ar[1][0] = fmaf(xr, wr0, fmaf(-xi, wi0, ar[1][0]));
      ai[1][0] = fmaf(xr, wi0, fmaf(xi, wr0, ai[1][0]));
      xr = blo(xb.y); xi = bhi(xb.y);
      ar[1][1] = fmaf(xr, wr1, fmaf(-xi, wi1, ar[1][1]));
      ai[1][1] = fmaf(xr, wi1, fmaf(xi, wr1, ai[1][1]));
    }
  } else {
    const u32* wb = (const u32*)w + (size_t)o * 32768 + m;
#pragma unroll 4
    for (int ic = 0; ic < 256; ++ic) {
      uint2 wp = *(const uint2*)&wb[(size_t)ic * 128];
      uint2 xa = *(const uint2*)&Xp[((size_t)ic * 32 + b0) * 128 + m];
      uint2 xb = *(const uint2*)&Xp[((size_t)ic * 32 + b0 + 1) * 128 + m];
      float wr0 = blo(wp.x), wi0 = bhi(wp.x), wr1 = blo(wp.y), wi1 = bhi(wp.y);
      float xr, xi;
      xr = blo(xa.x); xi = bhi(xa.x);
      ar[0][0] = fmaf(xr, wr0, fmaf(-xi, wi0, ar[0][0]));
      ai[0][0] = fmaf(xr, wi0, fmaf(xi, wr0, ai[0][0]));
      xr = blo(xa.y); xi = bhi(xa.y);
      ar[0][1] = fmaf(xr, wr1, fmaf(-xi, wi1, ar[0][1]));
      ai[0][1] = fmaf(xr, wi1, fmaf(xi, wr1, ai[0][1]));
      xr = blo(xb.x); xi = bhi(xb.x);
      ar[1][0] = fmaf(xr, wr0, fmaf(-xi, wi0, ar[1][0]));
      ai[1][0] = fmaf(xr, wi0, fmaf(xi, wr0, ai[1][0]));
      xr = blo(xb.y); xi = bhi(xb.y);
      ar[1][1] = fmaf(xr, wr1, fmaf(-xi, wi1, ar[1][1]));
      ai[1][1] = fmaf(xr, wi1, fmaf(xi, wr1, ai[1][1]));
    }
  }

  const float sIm = 2.0f / 4096.0f;
  const float sRe0 = (m == 0) ? (1.0f / 4096.0f) : (2.0f / 4096.0f);
  const float sRe1 = 2.0f / 4096.0f;
  u32* Yp32 = (u32*)Yp;
#pragma unroll
  for (int jb = 0; jb < 2; ++jb) {
    int b = b0 + jb;
    size_t base = ((size_t)(b * 256 + o)) * 128;   // u32 index
    u32 re = (u32)f2b(ar[jb][0] * sRe0) | ((u32)f2b(ar[jb][1] * sRe1) << 16);
    u32 im = (u32)f2b(ai[jb][0] * sIm) | ((u32)f2b(ai[jb][1] * sIm) << 16);
    Yp32[base + lane] = re;
    Yp32[base + 64 + lane] = im;
  }
}

// ---------------------------------------------------------------- launch
extern "C" void kernel_launch(void* const* d_in, const int* in_sizes, int n_in,
                              void* d_out, int out_size, void* d_ws, size_t ws_size,
                              hipStream_t stream) {
  const void* x = d_in[0];                // (32,256,4096) fp32 or bf16
  const void* w = d_in[1];                // (256,256,128,2) fp32 or bf16

  const int nz = (ws_size >= ((size_t)46 << 20)) ? 4 : 2;   // splitK parts

  char* ws = (char*)d_ws;
  int*   flag = (int*)(ws);
  u16*   Bas1 = (u16*)(ws + (1u << 20));                    // 2 MB
  u16*   Bas2 = (u16*)(ws + (3u << 20));                    // 2 MB
  float* Xt   = (float*)(ws + (5u << 20));                  // nz x 8 MB
  u32*   Xp   = (u32*)(ws + ((size_t)(5 + 8 * nz) << 20));  // 4 MB
  u16*   Yp   = (u16*)(ws + ((size_t)(9 + 8 * nz) << 20));  // 4 MB

  probe_kernel<<<dim3(1), dim3(256), 0, stream>>>((const u16*)x, flag);
  basis_kernel<<<dim3(4096), dim3(256), 0, stream>>>(Bas1, Bas2);

  // forward truncated rDFT, split-K=nz: x(8192x4096) * Bas1(256x4096)^T
  gemm_nt<64, 256, 0, true><<<dim3(1, 128, nz), dim3(256), 0, stream>>>(
      x, Bas1, MLEN / nz, MLEN, MLEN, Xt, NROWS, nullptr, nullptr, flag);

  // sum split-K parts + transpose to Xp[ic][b][m]
  pack_kernel<<<dim3(32, 8), dim3(256), 0, stream>>>(Xt, Xp, nz);

  // per-mode complex channel mix -> Yp (bf16, irfft scaling folded in)
  mix_kernel<<<dim3(128, 2), dim3(1024), 0, stream>>>(Xp, w, Yp, flag);

  // inverse DFT + LeakyReLU + residual
  gemm_nt<128, 128, 1, false><<<dim3(32, 64, 1), dim3(256), 0, stream>>>(
      Yp, Bas2, 256, 256, 256, nullptr, MLEN, x, d_out, flag);
}